// Round 1
// 646.959 us; speedup vs baseline: 1.0050x; 1.0050x over previous
//
#include <hip/hip_runtime.h>
#include <math.h>

// B=8, O=8, S=32, C=64, H=32, W=32, HID=C
#define Bc 8
#define Oc 8
#define Sc 32
#define Cc 64
#define HWc 1024
#define NBLK (Bc*Oc*Sc)     // 2048 blocks, one (b,o,s) sample each

typedef float f4 __attribute__((ext_vector_type(4)));

static __device__ __forceinline__ float hsum(f4 a) { return (a.x + a.y) + (a.z + a.w); }
static __device__ __forceinline__ float hmax(f4 a) { return fmaxf(fmaxf(a.x, a.y), fmaxf(a.z, a.w)); }
static __device__ __forceinline__ f4 vmax4(f4 a, f4 b) {
    f4 r; r.x = fmaxf(a.x, b.x); r.y = fmaxf(a.y, b.y);
    r.z = fmaxf(a.z, b.z); r.w = fmaxf(a.w, b.w); return r;
}

// Phase 1: 16-lane x 4-channel layout. Each channel's 1024 floats are reduced
//          by a 16-lane group (16 f4/lane, two interleaved accumulate chains),
//          then a 4-step butterfly (masks 8..1) instead of the old 6-step
//          wave64 butterfly: cross-lane ds ops drop 192 -> 32 per wave, and
//          16 loads are in flight per lane before the dependent reduce.
// Phase 2: wave0 = mean path, wave1 = max path; weight rows read as f4
//          (16 gather instrs per GEMM instead of 64 -> 4x fewer L1 line
//          lookups), LDS activations read as aligned f4 broadcasts.
__global__ __launch_bounds__(256) void ca_fused(const float* __restrict__ x,
                                                const float* __restrict__ w1,
                                                const float* __restrict__ w2,
                                                float* __restrict__ out) {
    __shared__ __align__(16) float s_mean[Cc];
    __shared__ __align__(16) float s_max[Cc];
    __shared__ __align__(16) float s_hm[Cc];
    __shared__ __align__(16) float s_hx[Cc];
    __shared__ __align__(16) float s_ax[Cc];

    const int blk   = blockIdx.x;            // (b*O + o)*S + s
    const int o     = (blk / Sc) % Oc;       // group index
    const int tid   = threadIdx.x;
    const int wave  = tid >> 6;
    const int lane  = tid & 63;
    const int sub   = lane >> 4;             // 0..3: channel within group-of-4
    const int chunk = lane & 15;             // 0..15: spatial chunk

    const f4* xb = (const f4*)(x + (size_t)blk * (Cc * HWc));

    // ---- Phase 1: pooling (mean + max over 1024 floats per channel) ----
    #pragma unroll
    for (int g = 0; g < 4; ++g) {
        const int c = wave * 16 + g * 4 + sub;
        const f4* p = xb + (size_t)c * 256 + chunk;   // 256 f4 per channel

        f4 a0 = __builtin_nontemporal_load(p);
        f4 a1 = __builtin_nontemporal_load(p + 16);
        f4 s0 = a0, m0 = a0;
        f4 s1 = a1, m1 = a1;
        #pragma unroll
        for (int k = 2; k < 16; k += 2) {
            f4 b0 = __builtin_nontemporal_load(p + k * 16);
            f4 b1 = __builtin_nontemporal_load(p + (k + 1) * 16);
            s0 += b0; m0 = vmax4(m0, b0);
            s1 += b1; m1 = vmax4(m1, b1);
        }
        float fs = hsum(s0 + s1);
        float fm = hmax(vmax4(m0, m1));

        // 4-step butterfly within each 16-lane group (2 chains interleave)
        #pragma unroll
        for (int msk = 8; msk >= 1; msk >>= 1) {
            fs += __shfl_xor(fs, msk, 64);
            fm = fmaxf(fm, __shfl_xor(fm, msk, 64));
        }
        if (chunk == 0) {
            s_mean[c] = fs * (1.0f / 1024.0f);
            s_max[c]  = fm;
        }
    }
    __syncthreads();

    // ---- Phase 2: grouped 64->64->64 MLP; wave0=mean path, wave1=max path ----
    float acc2 = 0.f;
    if (wave < 2) {
        const float* src = wave ? s_max : s_mean;
        const f4* wrow = (const f4*)(w1 + ((size_t)o * Cc + lane) * Cc);
        f4 a4 = {0.f, 0.f, 0.f, 0.f};
        #pragma unroll
        for (int c4 = 0; c4 < 16; ++c4)
            a4 += ((const f4*)src)[c4] * wrow[c4];
        float a = hsum(a4);
        (wave ? s_hx : s_hm)[lane] = fmaxf(a, 0.f);
    }
    __syncthreads();

    if (wave < 2) {
        const float* src = wave ? s_hx : s_hm;
        const f4* wrow = (const f4*)(w2 + ((size_t)o * Cc + lane) * Cc);
        f4 a4 = {0.f, 0.f, 0.f, 0.f};
        #pragma unroll
        for (int h4 = 0; h4 < 16; ++h4)
            a4 += ((const f4*)src)[h4] * wrow[h4];
        acc2 = hsum(a4);
        if (wave == 1) s_ax[lane] = acc2;
    }
    __syncthreads();

    if (wave == 0) {
        const float z = acc2 + s_ax[lane];
        out[(size_t)blk * Cc + lane] = 1.0f / (1.0f + __expf(-z));
    }
}

extern "C" void kernel_launch(void* const* d_in, const int* in_sizes, int n_in,
                              void* d_out, int out_size, void* d_ws, size_t ws_size,
                              hipStream_t stream) {
    const float* x  = (const float*)d_in[0];
    const float* w1 = (const float*)d_in[1];
    const float* w2 = (const float*)d_in[2];
    float* out = (float*)d_out;

    ca_fused<<<NBLK, 256, 0, stream>>>(x, w1, w2, out);
}